// Round 10
// baseline (235.986 us; speedup 1.0000x reference)
//
#include <hip/hip_runtime.h>

// B=4, T=2048, C=1024, H=16, HS=64
typedef __attribute__((ext_vector_type(8))) short v8s;
typedef __attribute__((ext_vector_type(4))) short v4s;
typedef __attribute__((ext_vector_type(4))) float v4f;

static __device__ __forceinline__ short f2bf(float f) {
  union { float f; unsigned u; } c; c.f = f;
  unsigned r = c.u + 0x7fffu + ((c.u >> 16) & 1u);
  return (short)(r >> 16);
}

// round-half-up pack of two f32 -> bf16x2
static __device__ __forceinline__ unsigned pk_bf16(float a, float b) {
  union { float f; unsigned u; } ca, cb; ca.f = a; cb.f = b;
  return ((ca.u + 0x8000u) >> 16) | ((cb.u + 0x8000u) & 0xffff0000u);
}

#if __has_builtin(__builtin_amdgcn_exp2f)
#define EXP2(x) __builtin_amdgcn_exp2f(x)
#else
#define EXP2(x) exp2f(x)
#endif

#define GLDS(gp, lp) __builtin_amdgcn_global_load_lds( \
    (const __attribute__((address_space(1))) void*)(gp), \
    (__attribute__((address_space(3))) void*)(lp), 16, 0, 0)

// ---------------- fused prep kernel ----------------
// blocks [0,8192): x f32->bf16; [8192,9216): Wo f32->bf16; [9216,9984): build Wt.

__global__ __launch_bounds__(256) void prep(const float* __restrict__ x,
                                            const float* __restrict__ Wq,
                                            const float* __restrict__ Wk,
                                            const float* __restrict__ Wv,
                                            const float* __restrict__ Wo,
                                            short* __restrict__ Xb,
                                            short* __restrict__ Wot,
                                            short* __restrict__ Wt) {
  __shared__ float tile[64][65];
  const int blk = blockIdx.x;
  const int tid = threadIdx.x;
  if (blk < 9216) {                     // cast paths
    const float* src = (blk < 8192) ? x : Wo;
    short* dst = (blk < 8192) ? Xb : Wot;
    const int b2 = (blk < 8192) ? blk : (blk - 8192);
    const int idx = (b2 * 256 + tid) * 4;
    float4 v = *(const float4*)(src + idx);
    v4s o; o.x = f2bf(v.x); o.y = f2bf(v.y); o.z = f2bf(v.z); o.w = f2bf(v.w);
    *(v4s*)(dst + idx) = o;
    return;
  }
  // build_wt: Wq/Wk/Wv [H][C][HS] -> Wt [3072][1024] (row n = sel*1024+h*64+d, col k = c)
  const int bb = blk - 9216;            // 0..767
  const int sel = bb >> 8, rest = bb & 255;
  const int h = rest >> 4, kt = rest & 15;
  const float* W = (sel == 0) ? Wq : ((sel == 1) ? Wk : Wv);
  const int k0 = kt * 64;
  for (int i = 0; i < 4; ++i) {
    int c = i * 256 + tid;              // 1024 float4 chunks
    int row = c >> 4, c4 = (c & 15) * 4;
    float4 v = *(const float4*)(W + (size_t)h * 65536 + (size_t)(k0 + row) * 64 + c4);
    tile[row][c4 + 0] = v.x; tile[row][c4 + 1] = v.y;
    tile[row][c4 + 2] = v.z; tile[row][c4 + 3] = v.w;
  }
  __syncthreads();
  for (int i = 0; i < 2; ++i) {
    int c = i * 256 + tid;              // 512 v8s chunks
    int d = c >> 3, k8 = (c & 7) * 8;
    v8s o;
    for (int j = 0; j < 8; ++j) o[j] = f2bf(tile[k8 + j][d]);
    *(v8s*)(Wt + (size_t)(sel * 1024 + h * 64 + d) * 1024 + k0 + k8) = o;
  }
}

// ---------------- QKV GEMM: [8192x1024] @ Wt^T (Wt is [3072][1024]) ----------------
// Round-1 schedule, BK=64 + triple buffer: BM=256 BN=128 BK=64, 3 LDS bufs
// (3 x 48 KB = 144 KB, still 1 block/CU), 512 thr = 8 waves (4M x 2N), grid
// 32x24 = 768 = 3 block-waves. 16 K-steps, ONE barrier per step (half of BK=32),
// depth-2 tile prefetch with counted vmcnt(6): at each barrier only t+2's 6 loads
// outstanding -> t+1 proven resident. Two 16-MFMA clusters per step (k-slices).
// Swizzle: 16B col-block cb ^= (row&7) via pre-swizzled GLOBAL source + linear
// GLDS dest; ds_read applies same XOR. Epilogue: Q pre-scaled by (1/8)*log2(e)
// (folds softmax scale into Q; attn then does exp2(s) directly); K plain;
// V written directly transposed -> Vt [bh][64][T].

#define GQ_STAGE_A(P, T) do {                                                     \
  _Pragma("unroll") for (int i_ = 0; i_ < 4; ++i_)                                \
    GLDS(Xb + (size_t)(m0 + rA + i_ * 64) * 1024 + (T) * 64 + cbl * 8,            \
         lds + (P) * 16384 + (tid + i_ * 512) * 8); } while (0)

#define GQ_STAGE_B(P, T) do {                                                     \
  _Pragma("unroll") for (int i_ = 0; i_ < 2; ++i_)                                \
    GLDS(Wt + (size_t)(n0 + rA + i_ * 64) * 1024 + (T) * 64 + cbl * 8,            \
         lds + 49152 + (P) * 8192 + (tid + i_ * 512) * 8); } while (0)

__global__ __launch_bounds__(512) void gemm_qkv(const short* __restrict__ Xb,
                                                const short* __restrict__ Wt,
                                                short* __restrict__ Qo,
                                                short* __restrict__ Ko,
                                                short* __restrict__ Vt) {
  __shared__ short lds[73728];          // 144 KB: A bufs 3x[256][64] | B bufs 3x[128][64]
  const int tid = threadIdx.x;
  const int lane = tid & 63, quad = lane >> 4, l16 = lane & 15;
  const int wave = tid >> 6;
  const int m0 = blockIdx.x * 256, n0 = blockIdx.y * 128;
  const int wm = (wave >> 1) * 64, wn = (wave & 1) * 64;

  // staging source (pre-swizzled): chunk c -> row = c>>3, col-block (c&7)^(row&7)
  const int rA = tid >> 3;              // 0..63; A rows rA+{0,64,128,192}, B rows rA+{0,64}
  const int cbl = (tid & 7) ^ (rA & 7);

  // fragment read offsets (shorts)
  const int swz = l16 & 7;
  const int csw0 = (quad ^ swz) * 8;            // k-slice 0 (k 0..31)
  const int csw1 = ((4 + quad) ^ swz) * 8;      // k-slice 1 (k 32..63)
  int aoff[4], boff[4];
#pragma unroll
  for (int mt = 0; mt < 4; ++mt) aoff[mt] = (wm + mt * 16 + l16) * 64;
#pragma unroll
  for (int nt = 0; nt < 4; ++nt) boff[nt] = (wn + nt * 16 + l16) * 64;

  v4f acc[4][4];
#pragma unroll
  for (int i = 0; i < 4; ++i)
#pragma unroll
    for (int j = 0; j < 4; ++j) acc[i][j] = (v4f){0.f, 0.f, 0.f, 0.f};

  // prologue: stage tiles 0 (buf0) and 1 (buf1); tile0 resident, tile1 in flight
  GQ_STAGE_A(0, 0); GQ_STAGE_B(0, 0);
  GQ_STAGE_A(1, 1); GQ_STAGE_B(1, 1);
  asm volatile("s_waitcnt vmcnt(6)" ::: "memory");
  __builtin_amdgcn_s_barrier();

  int p = 0, pn = 2;                    // current buf, prefetch buf = (t+2)%3
#pragma unroll 1
  for (int t = 0; t < 16; ++t) {
    int tn = t + 2; if (tn > 15) tn = 15;      // clamped re-stage keeps vmcnt uniform
    const short* lAp = lds + p * 16384;
    const short* lBp = lds + 49152 + p * 8192;

    // ---- cluster 0: k-slice 0; stage next A tile ----
    GQ_STAGE_A(pn, tn);
    v8s a[4], b[4];
#pragma unroll
    for (int mt = 0; mt < 4; ++mt) a[mt] = *(const v8s*)(lAp + aoff[mt] + csw0);
#pragma unroll
    for (int nt = 0; nt < 4; ++nt) b[nt] = *(const v8s*)(lBp + boff[nt] + csw0);
    __builtin_amdgcn_s_setprio(1);
#pragma unroll
    for (int mt = 0; mt < 4; ++mt)
#pragma unroll
      for (int nt = 0; nt < 4; ++nt)
        acc[mt][nt] = __builtin_amdgcn_mfma_f32_16x16x32_bf16(a[mt], b[nt], acc[mt][nt], 0, 0, 0);
    __builtin_amdgcn_s_setprio(0);

    // ---- cluster 1: k-slice 1; stage next B tile ----
    GQ_STAGE_B(pn, tn);
#pragma unroll
    for (int mt = 0; mt < 4; ++mt) a[mt] = *(const v8s*)(lAp + aoff[mt] + csw1);
#pragma unroll
    for (int nt = 0; nt < 4; ++nt) b[nt] = *(const v8s*)(lBp + boff[nt] + csw1);
    __builtin_amdgcn_s_setprio(1);
#pragma unroll
    for (int mt = 0; mt < 4; ++mt)
#pragma unroll
      for (int nt = 0; nt < 4; ++nt)
        acc[mt][nt] = __builtin_amdgcn_mfma_f32_16x16x32_bf16(a[mt], b[nt], acc[mt][nt], 0, 0, 0);
    __builtin_amdgcn_s_setprio(0);

    // counted wait: only t+2's 6 loads may remain outstanding -> t+1 resident
    asm volatile("s_waitcnt vmcnt(6) lgkmcnt(0)" ::: "memory");
    __builtin_amdgcn_s_barrier();
    p = (p == 2) ? 0 : p + 1;
    pn = (pn == 2) ? 0 : pn + 1;
  }
  asm volatile("s_waitcnt vmcnt(0)" ::: "memory");  // drain clamped tail loads

  // ---- epilogue ----
  const int selu = n0 >> 10;            // uniform per block (128 | 1024)
  if (selu < 2) {
    short* obase = (selu == 0) ? Qo : Ko;
    const float sc = (selu == 0) ? 0.18033688011112042f : 1.0f;  // fold softmax scale into Q
#pragma unroll
    for (int nt = 0; nt < 4; ++nt) {
      int n = (n0 + wn + nt * 16 + l16) & 1023;
      int h = n >> 6, d = n & 63;
#pragma unroll
      for (int mt = 0; mt < 4; ++mt) {
        int m = m0 + wm + mt * 16 + quad * 4;
        int b_ = m >> 11, tt_ = m & 2047;
        size_t base = (size_t)((b_ * 16 + h) * 2048 + tt_) * 64 + d;
#pragma unroll
        for (int r = 0; r < 4; ++r)
          obase[base + (size_t)r * 64] = f2bf(acc[mt][nt][r] * sc);
      }
    }
  } else {
    // V: write directly transposed -> Vt [bh][64][2048]
#pragma unroll
    for (int nt = 0; nt < 4; ++nt) {
      int n = (n0 + wn + nt * 16 + l16) & 1023;
      int h = n >> 6, d = n & 63;
#pragma unroll
      for (int mt = 0; mt < 4; ++mt) {
        int m = m0 + wm + mt * 16 + quad * 4;
        int b_ = m >> 11, tt_ = m & 2047;
        int2 dw;
        dw.x = (int)pk_bf16(acc[mt][nt][0], acc[mt][nt][1]);
        dw.y = (int)pk_bf16(acc[mt][nt][2], acc[mt][nt][3]);
        *(int2*)(Vt + ((size_t)(b_ * 16 + h) * 64 + d) * 2048 + tt_) = dw;
      }
    }
  }
}

// ---------------- flash attention (S^T form, pipelined LDS-staged K/V) -------------
// grid: 1024 blocks = 64 bh x 16 chunk-slots; target 4 blocks/CU (LDS 40 KB x 4 =
// 160 KB; VGPR must stay <=128 -> launch_bounds(256,2), NOT (256,4): the hard cap
// forced 64 VGPR + scratch spills (401 MB writes, 3x regression, round 7)).
// Slot->chunk nibble-LUT: each CU's slot set {s,s+4,s+8,s+12} sums to 68 tiles.
// block 256 = 4 waves x 32 q-rows = 128 q-rows (one chunk per block).
// Pipeline (T14/T3): lK/lV double-buffered; tile t+1's GLDS issued before tile t's
// compute; counted vmcnt(4) (drain 0 only on last tile).
// Register discipline: QK^T for BOTH qs first into sT[2][4] (aK live), aK dies,
// THEN load aV and run exp/pack/PV per qs -> peak co-live ~120 VGPR.
// lP: per-wave 16-row XOR-swizzled region (8 KB), qs-sequential write->read (wave-
// private, in-order DS). Softmax: fixed-max exp2; Q pre-scaled by (1/8)log2(e) in
// gemm_qkv epilogue -> exp2(s) directly, no per-element multiply. Sum deferred.

#define ASTAGE(P, KB)                                                             \
  GLDS(K + qkbase + (size_t)((KB) + r0) * 64 + cl0 * 8, lK + (P) * 4096 + tid * 8);          \
  GLDS(K + qkbase + (size_t)((KB) + r1) * 64 + cl1 * 8, lK + (P) * 4096 + tid * 8 + 2048);   \
  GLDS(Vt + vtbase + (size_t)r0 * 2048 + (KB) + cl0 * 8, lV + (P) * 4096 + tid * 8);         \
  GLDS(Vt + vtbase + (size_t)r1 * 2048 + (KB) + cl1 * 8, lV + (P) * 4096 + tid * 8 + 2048)

__global__ __launch_bounds__(256, 2) void attn(const short* __restrict__ Q,
                                               const short* __restrict__ K,
                                               const short* __restrict__ Vt,
                                               short* __restrict__ AO) {
  __shared__ short lK[2 * 64 * 64];     // 16 KB double-buffered K tiles (swizzled)
  __shared__ short lV[2 * 64 * 64];     // 16 KB double-buffered V^T tiles (swizzled)
  __shared__ short lP[4 * 16 * 64];     // 8 KB P round-trip (per-wave 16x64 swizzled)
  const int tid = threadIdx.x;
  const int w = tid >> 6, lane = tid & 63, quad = lane >> 4, l16 = lane & 15;
  const int bh = blockIdx.x & 63;
  const int slot = blockIdx.x >> 6;     // 0..15
  const int c = (int)((0x5410672398DCABEFull >> (slot * 4)) & 15ull);
  const unsigned psel = 0x07060302u;        // v_perm: {hi16(b), hi16(a)}
  short* pw = lP + w * 1024;                // 16 rows x 64 cols (swizzled)
  const size_t qkbase = (size_t)bh * 2048 * 64;
  const size_t vtbase = (size_t)bh * 64 * 2048;
  const int b_ = bh >> 4, h = bh & 15;

  // staging map: thread handles chunks c0=tid, c1=tid+256 of each tile
  const int r0 = tid >> 3, cp = tid & 7;
  const int cl0 = cp ^ (r0 & 7);
  const int r1 = r0 + 32;
  const int cl1 = cp ^ (r1 & 7);

  // fragment LDS offsets (shorts): row*64 + (col8log ^ (l16&7))*8
  const int swz = l16 & 7;
  const int ph0 = (quad ^ swz) * 8;           // col8log = quad   (k 0..31)
  const int ph1 = ((quad + 4) ^ swz) * 8;     // col8log = quad+4 (k 32..63)

  const int qc = c * 128 + w * 32;            // this wave's first q-row

  // Q fragments (B-operand of S^T): B[k=d][n=qrow], two 16-row subsets
  v8s bQ[2][2];
#pragma unroll
  for (int qs = 0; qs < 2; ++qs) {
    const short* qb = Q + qkbase + (size_t)(qc + qs * 16 + l16) * 64 + quad * 8;
    bQ[qs][0] = *(const v8s*)(qb);
    bQ[qs][1] = *(const v8s*)(qb + 32);
  }
  v4f accO[2][4];
#pragma unroll
  for (int qs = 0; qs < 2; ++qs)
#pragma unroll
    for (int g = 0; g < 4; ++g) accO[qs][g] = (v4f){0.f, 0.f, 0.f, 0.f};
  float lrun[2] = {0.f, 0.f};

  const int nst = 2 * c + 2;                  // 64-key tiles covering the 128-row chunk

  ASTAGE(0, 0);                               // stage tile 0

  for (int kt = 0; kt < nst; ++kt) {
    const int p = kt & 1;
    const int kb = kt * 64;
    if (kt + 1 < nst) {                 // block-uniform
      ASTAGE(p ^ 1, kb + 64);           // issue next tile into the other buffer
      asm volatile("s_waitcnt vmcnt(4)" ::: "memory");   // current tile resident
    } else {
      asm volatile("s_waitcnt vmcnt(0)" ::: "memory");
    }
    __builtin_amdgcn_s_barrier();       // staged data visible to all waves
    const short* lKp = lK + p * 4096;
    const short* lVp = lV + p * 4096;

    const bool act0 = kb < qc + 16;     // qs=0 has unmasked keys this stage
    const bool act1 = kb < qc + 32;     // qs=1 (superset of act0)
    if (act1) {                         // wave-uniform
      // ---- phase A: K fragments + QK^T for both q-subsets (aK dies after) ----
      v4f sT[2][4];
      {
        v8s aK[4][2];
#pragma unroll
        for (int mt = 0; mt < 4; ++mt) {
          const short* kr = lKp + (mt * 16 + l16) * 64;
          aK[mt][0] = *(const v8s*)(kr + ph0);
          aK[mt][1] = *(const v8s*)(kr + ph1);
        }
        __builtin_amdgcn_s_setprio(1);
#pragma unroll
        for (int qs = 0; qs < 2; ++qs) {
          if (qs == 0 ? !act0 : false) continue;
#pragma unroll
          for (int mt = 0; mt < 4; ++mt) {
            v4f t = (v4f){0.f, 0.f, 0.f, 0.f};
            t = __builtin_amdgcn_mfma_f32_16x16x32_bf16(aK[mt][0], bQ[qs][0], t, 0, 0, 0);
            t = __builtin_amdgcn_mfma_f32_16x16x32_bf16(aK[mt][1], bQ[qs][1], t, 0, 0, 0);
            sT[qs][mt] = t;
          }
        }
        __builtin_amdgcn_s_setprio(0);
      }
      // ---- phase B: V fragments + per-qs exp/pack/PV (shared 16-row lP) ----
      v8s aV[4][2];
#pragma unroll
      for (int g = 0; g < 4; ++g) {
        const short* vr = lVp + (g * 16 + l16) * 64;
        aV[g][0] = *(const v8s*)(vr + ph0);
        aV[g][1] = *(const v8s*)(vr + ph1);
      }
#pragma unroll
      for (int qs = 0; qs < 2; ++qs) {
        if (qs == 0 ? !act0 : false) continue;
        const int rbase = qc + qs * 16;
        if (kb + 63 >= rbase) {         // diagonal-overlap: element mask
          const int kq = kb + quad * 4 - (rbase + l16);
#pragma unroll
          for (int mt = 0; mt < 4; ++mt)
#pragma unroll
            for (int r = 0; r < 4; ++r)
              if (kq + mt * 16 + r > 0) sT[qs][mt][r] = -__builtin_inff();
        }
        float ls = lrun[qs];
#pragma unroll
        for (int mt = 0; mt < 4; ++mt) {
          float p0 = EXP2(sT[qs][mt][0]);   // Q pre-scaled: exp2 directly
          float p1 = EXP2(sT[qs][mt][1]);
          float p2 = EXP2(sT[qs][mt][2]);
          float p3 = EXP2(sT[qs][mt][3]);
          ls += (p0 + p1) + (p2 + p3);
          int2 dw;
          dw.x = (int)__builtin_amdgcn_perm(__float_as_uint(p1), __float_as_uint(p0), psel);
          dw.y = (int)__builtin_amdgcn_perm(__float_as_uint(p3), __float_as_uint(p2), psel);
          // swizzled write: row l16, cols mt*16+quad*4 .. +3 (XOR on 16B block idx)
          *(int2*)&pw[l16 * 64 + ((mt * 16 + quad * 4) ^ (swz * 8))] = dw;
        }
        lrun[qs] = ls;
        // ---- PV: read this qs's P (same swizzle pattern as K/V reads) ----
        v8s bP0 = *(const v8s*)&pw[l16 * 64 + ph0];
        v8s bP1 = *(const v8s*)&pw[l16 * 64 + ph1];
        __builtin_amdgcn_s_setprio(1);
#pragma unroll
        for (int g = 0; g < 4; ++g) {
          accO[qs][g] = __builtin_amdgcn_mfma_f32_16x16x32_bf16(aV[g][0], bP0, accO[qs][g], 0, 0, 0);
          accO[qs][g] = __builtin_amdgcn_mfma_f32_16x16x32_bf16(aV[g][1], bP1, accO[qs][g], 0, 0, 0);
        }
        __builtin_amdgcn_s_setprio(0);
      }
    }
    __builtin_amdgcn_s_barrier();       // all reads of buf p done before it's re-staged
  }

  // ---- epilogue: finish row-sums (across the 4 quads), normalize, store O^T ----
#pragma unroll
  for (int qs = 0; qs < 2; ++qs) {
    float ls = lrun[qs];
    ls += __shfl_xor(ls, 16);
    ls += __shfl_xor(ls, 32);
    float inv = __builtin_amdgcn_rcpf(ls);
    int t = qc + qs * 16 + l16;
    short* ao = AO + ((size_t)(b_ * 2048 + t)) * 1024 + h * 64 + quad * 4;
#pragma unroll
    for (int g = 0; g < 4; ++g) {
      int2 dw;
      dw.x = (int)pk_bf16(accO[qs][g][0] * inv, accO[qs][g][1] * inv);
      dw.y = (int)pk_bf16(accO[qs][g][2] * inv, accO[qs][g][3] * inv);
      *(int2*)(ao + g * 16) = dw;       // d = g*16 + quad*4 + {0..3}
    }
  }
}

#undef ASTAGE

// ---------------- output projection: out = AO @ Wo^T + bo (fp32 out) ----------------
// Same round-1 structure: BM=256 BN=128 BK=32, quad-buffer, 512 thr, grid 32x8 = 256
// blocks = exactly 1 block-wave (1 block/CU).

__global__ __launch_bounds__(512) void gemm_out(const short* __restrict__ AO,
                                                const short* __restrict__ Wot,
                                                const float* __restrict__ bo,
                                                float* __restrict__ out) {
  __shared__ short lds[49152];          // 96 KB: A bufs [4][256][32] | B bufs [4][128][32]
  const int tid = threadIdx.x;
  const int lane = tid & 63, quad = lane >> 4, l16 = lane & 15;
  const int wave = tid >> 6;
  const int m0 = blockIdx.x * 256, n0 = blockIdx.y * 128;
  const int wm = (wave >> 1) * 64, wn = (wave & 1) * 64;

  const int r0 = tid >> 2, cbs = (tid & 3) ^ ((r0 >> 1) & 3);
  const size_t offA0 = (size_t)(m0 + r0) * 1024 + cbs * 8;
  const size_t offB0 = (size_t)(n0 + r0) * 1024 + cbs * 8;

  int aoff[4], boff[4];
#pragma unroll
  for (int mt = 0; mt < 4; ++mt) {
    int row = wm + mt * 16 + l16;
    aoff[mt] = row * 32 + (quad ^ ((row >> 1) & 3)) * 8;
  }
#pragma unroll
  for (int nt = 0; nt < 4; ++nt) {
    int row = wn + nt * 16 + l16;
    boff[nt] = row * 32 + (quad ^ ((row >> 1) & 3)) * 8;
  }

  v4f acc[4][4];
#pragma unroll
  for (int i = 0; i < 4; ++i)
#pragma unroll
    for (int j = 0; j < 4; ++j) acc[i][j] = (v4f){0.f, 0.f, 0.f, 0.f};

#pragma unroll
  for (int t = 0; t < 3; ++t) {
    GLDS(AO + offA0 + t * 32, lds + t * 8192 + tid * 8);
    GLDS(AO + offA0 + 131072 + t * 32, lds + t * 8192 + 4096 + tid * 8);
    GLDS(Wot + offB0 + t * 32, lds + 32768 + t * 4096 + tid * 8);
  }
  asm volatile("s_waitcnt vmcnt(6)" ::: "memory");
  __builtin_amdgcn_s_barrier();

#pragma unroll 4
  for (int t = 0; t < 32; ++t) {
    const int p = t & 3;
    int tn = t + 3; if (tn > 31) tn = 31;
    const int pn = (t + 3) & 3;
    const short* lAp = lds + p * 8192;
    const short* lBp = lds + 32768 + p * 4096;

    GLDS(AO + offA0 + tn * 32, lds + pn * 8192 + tid * 8);
    GLDS(AO + offA0 + 131072 + tn * 32, lds + pn * 8192 + 4096 + tid * 8);
    v8s a[4], b[2];
#pragma unroll
    for (int mt = 0; mt < 4; ++mt) a[mt] = *(const v8s*)(lAp + aoff[mt]);
    b[0] = *(const v8s*)(lBp + boff[0]);
    b[1] = *(const v8s*)(lBp + boff[1]);
    __builtin_amdgcn_s_setprio(1);
#pragma unroll
    for (int mt = 0; mt < 4; ++mt) {
      acc[mt][0] = __builtin_amdgcn_mfma_f32_16x16x32_bf16(a[mt], b[0], acc[mt][0], 0, 0, 0);
      acc[mt][1] = __builtin_amdgcn_mfma_f32_16x16x32_bf16(a[mt], b[1], acc[mt][1], 0, 0, 0);
    }
    __builtin_amdgcn_s_setprio(0);

    GLDS(Wot + offB0 + tn * 32, lds + 32768 + pn * 4096 + tid * 8);
    b[0] = *(const v8s*)(lBp + boff[2]);
    b[1] = *(const v8s*)(lBp + boff[3]);
    __builtin_amdgcn_s_setprio(1);
#pragma unroll
    for (int mt = 0; mt < 4; ++mt) {
      acc[mt][2] = __builtin_amdgcn_mfma_f32_16x16x32_bf16(a[mt], b[0], acc[mt][2], 0, 0, 0);
      acc[mt][3] = __builtin_amdgcn_mfma_f32_16x16x32_bf16(a[mt], b[1], acc[mt][3], 0, 0, 0);
    }
    __builtin_amdgcn_s_setprio(0);

    asm volatile("s_waitcnt vmcnt(6) lgkmcnt(0)" ::: "memory");
    __builtin_amdgcn_s_barrier();
  }

  // epilogue: fp32 + bias
#pragma unroll
  for (int nt = 0; nt < 4; ++nt) {
    int n = n0 + wn + nt * 16 + l16;
    float bias = bo[n];
#pragma unroll
    for (int mt = 0; mt < 4; ++mt) {
      int m = m0 + wm + mt * 16 + quad * 4;
#pragma unroll
      for (int r = 0; r < 4; ++r)
        out[(size_t)(m + r) * 1024 + n] = acc[mt][nt][r] + bias;
    }
  }
}

// ---------------- launch ----------------

extern "C" void kernel_launch(void* const* d_in, const int* in_sizes, int n_in,
                              void* d_out, int out_size, void* d_ws, size_t ws_size,
                              hipStream_t stream) {
  const float* x  = (const float*)d_in[0];
  const float* Wq = (const float*)d_in[1];
  const float* Wk = (const float*)d_in[2];
  const float* Wv = (const float*)d_in[3];
  const float* Wo = (const float*)d_in[4];
  const float* bo = (const float*)d_in[5];
  float* out = (float*)d_out;
  char* ws = (char*)d_ws;

  short* Xb  = (short*)(ws);                          // 16 MB (reused as AO after QKV GEMM)
  short* Wt  = (short*)(ws + (16u << 20));            // 6 MB
  short* Wot = (short*)(ws + (22u << 20));            // 2 MB
  short* Q   = (short*)(ws + (24u << 20));            // 16 MB
  short* K   = (short*)(ws + (40u << 20));            // 16 MB
  short* Vt  = (short*)(ws + (56u << 20));            // 16 MB  -> total 72 MB

  prep<<<9984, 256, 0, stream>>>(x, Wq, Wk, Wv, Wo, Xb, Wot, Wt);
  gemm_qkv<<<dim3(32, 24), 512, 0, stream>>>(Xb, Wt, Q, K, Vt);
  attn<<<1024, 256, 0, stream>>>(Q, K, Vt, Xb);  // AO aliases Xb, 16 slots/bh
  gemm_out<<<dim3(32, 8), 512, 0, stream>>>(Xb, Wot, bo, out);
}

// Round 11
// 228.695 us; speedup vs baseline: 1.0319x; 1.0319x over previous
//
#include <hip/hip_runtime.h>

// B=4, T=2048, C=1024, H=16, HS=64
typedef __attribute__((ext_vector_type(8))) short v8s;
typedef __attribute__((ext_vector_type(4))) short v4s;
typedef __attribute__((ext_vector_type(4))) float v4f;

static __device__ __forceinline__ short f2bf(float f) {
  union { float f; unsigned u; } c; c.f = f;
  unsigned r = c.u + 0x7fffu + ((c.u >> 16) & 1u);
  return (short)(r >> 16);
}

// round-half-up pack of two f32 -> bf16x2
static __device__ __forceinline__ unsigned pk_bf16(float a, float b) {
  union { float f; unsigned u; } ca, cb; ca.f = a; cb.f = b;
  return ((ca.u + 0x8000u) >> 16) | ((cb.u + 0x8000u) & 0xffff0000u);
}

#if __has_builtin(__builtin_amdgcn_exp2f)
#define EXP2(x) __builtin_amdgcn_exp2f(x)
#else
#define EXP2(x) exp2f(x)
#endif

#define GLDS(gp, lp) __builtin_amdgcn_global_load_lds( \
    (const __attribute__((address_space(1))) void*)(gp), \
    (__attribute__((address_space(3))) void*)(lp), 16, 0, 0)

// ---------------- fused prep kernel ----------------
// blocks [0,8192): x f32->bf16; [8192,9216): Wo f32->bf16; [9216,9984): build Wt.

__global__ __launch_bounds__(256) void prep(const float* __restrict__ x,
                                            const float* __restrict__ Wq,
                                            const float* __restrict__ Wk,
                                            const float* __restrict__ Wv,
                                            const float* __restrict__ Wo,
                                            short* __restrict__ Xb,
                                            short* __restrict__ Wot,
                                            short* __restrict__ Wt) {
  __shared__ float tile[64][65];
  const int blk = blockIdx.x;
  const int tid = threadIdx.x;
  if (blk < 9216) {                     // cast paths
    const float* src = (blk < 8192) ? x : Wo;
    short* dst = (blk < 8192) ? Xb : Wot;
    const int b2 = (blk < 8192) ? blk : (blk - 8192);
    const int idx = (b2 * 256 + tid) * 4;
    float4 v = *(const float4*)(src + idx);
    v4s o; o.x = f2bf(v.x); o.y = f2bf(v.y); o.z = f2bf(v.z); o.w = f2bf(v.w);
    *(v4s*)(dst + idx) = o;
    return;
  }
  // build_wt: Wq/Wk/Wv [H][C][HS] -> Wt [3072][1024] (row n = sel*1024+h*64+d, col k = c)
  const int bb = blk - 9216;            // 0..767
  const int sel = bb >> 8, rest = bb & 255;
  const int h = rest >> 4, kt = rest & 15;
  const float* W = (sel == 0) ? Wq : ((sel == 1) ? Wk : Wv);
  const int k0 = kt * 64;
  for (int i = 0; i < 4; ++i) {
    int c = i * 256 + tid;              // 1024 float4 chunks
    int row = c >> 4, c4 = (c & 15) * 4;
    float4 v = *(const float4*)(W + (size_t)h * 65536 + (size_t)(k0 + row) * 64 + c4);
    tile[row][c4 + 0] = v.x; tile[row][c4 + 1] = v.y;
    tile[row][c4 + 2] = v.z; tile[row][c4 + 3] = v.w;
  }
  __syncthreads();
  for (int i = 0; i < 2; ++i) {
    int c = i * 256 + tid;              // 512 v8s chunks
    int d = c >> 3, k8 = (c & 7) * 8;
    v8s o;
    for (int j = 0; j < 8; ++j) o[j] = f2bf(tile[k8 + j][d]);
    *(v8s*)(Wt + (size_t)(sel * 1024 + h * 64 + d) * 1024 + k0 + k8) = o;
  }
}

// ---------------- QKV GEMM: [8192x1024] @ Wt^T (Wt is [3072][1024]) ----------------
// BK=64 + triple buffer (measured 65.8 -> 60.3 us vs BK=32): BM=256 BN=128 BK=64,
// 3 LDS bufs (144 KB, 1 block/CU), 512 thr = 8 waves (4M x 2N), grid 32x24 = 768 =
// 3 block-waves. 16 K-steps, ONE barrier per step, depth-2 tile prefetch with
// counted vmcnt(6). Two 16-MFMA clusters per step (k-slices).
// Swizzle: 16B col-block cb ^= (row&7) via pre-swizzled GLOBAL source + linear
// GLDS dest; ds_read applies same XOR. Epilogue: Q pre-scaled by (1/8)*log2(e)
// (folds softmax scale; attn does exp2(s) directly); V written transposed -> Vt.

#define GQ_STAGE_A(P, T) do {                                                     \
  _Pragma("unroll") for (int i_ = 0; i_ < 4; ++i_)                                \
    GLDS(Xb + (size_t)(m0 + rA + i_ * 64) * 1024 + (T) * 64 + cbl * 8,            \
         lds + (P) * 16384 + (tid + i_ * 512) * 8); } while (0)

#define GQ_STAGE_B(P, T) do {                                                     \
  _Pragma("unroll") for (int i_ = 0; i_ < 2; ++i_)                                \
    GLDS(Wt + (size_t)(n0 + rA + i_ * 64) * 1024 + (T) * 64 + cbl * 8,            \
         lds + 49152 + (P) * 8192 + (tid + i_ * 512) * 8); } while (0)

__global__ __launch_bounds__(512) void gemm_qkv(const short* __restrict__ Xb,
                                                const short* __restrict__ Wt,
                                                short* __restrict__ Qo,
                                                short* __restrict__ Ko,
                                                short* __restrict__ Vt) {
  __shared__ short lds[73728];          // 144 KB: A bufs 3x[256][64] | B bufs 3x[128][64]
  const int tid = threadIdx.x;
  const int lane = tid & 63, quad = lane >> 4, l16 = lane & 15;
  const int wave = tid >> 6;
  const int m0 = blockIdx.x * 256, n0 = blockIdx.y * 128;
  const int wm = (wave >> 1) * 64, wn = (wave & 1) * 64;

  // staging source (pre-swizzled): chunk c -> row = c>>3, col-block (c&7)^(row&7)
  const int rA = tid >> 3;              // 0..63; A rows rA+{0,64,128,192}, B rows rA+{0,64}
  const int cbl = (tid & 7) ^ (rA & 7);

  // fragment read offsets (shorts)
  const int swz = l16 & 7;
  const int csw0 = (quad ^ swz) * 8;            // k-slice 0 (k 0..31)
  const int csw1 = ((4 + quad) ^ swz) * 8;      // k-slice 1 (k 32..63)
  int aoff[4], boff[4];
#pragma unroll
  for (int mt = 0; mt < 4; ++mt) aoff[mt] = (wm + mt * 16 + l16) * 64;
#pragma unroll
  for (int nt = 0; nt < 4; ++nt) boff[nt] = (wn + nt * 16 + l16) * 64;

  v4f acc[4][4];
#pragma unroll
  for (int i = 0; i < 4; ++i)
#pragma unroll
    for (int j = 0; j < 4; ++j) acc[i][j] = (v4f){0.f, 0.f, 0.f, 0.f};

  // prologue: stage tiles 0 (buf0) and 1 (buf1); tile0 resident, tile1 in flight
  GQ_STAGE_A(0, 0); GQ_STAGE_B(0, 0);
  GQ_STAGE_A(1, 1); GQ_STAGE_B(1, 1);
  asm volatile("s_waitcnt vmcnt(6)" ::: "memory");
  __builtin_amdgcn_s_barrier();

  int p = 0, pn = 2;                    // current buf, prefetch buf = (t+2)%3
#pragma unroll 1
  for (int t = 0; t < 16; ++t) {
    int tn = t + 2; if (tn > 15) tn = 15;      // clamped re-stage keeps vmcnt uniform
    const short* lAp = lds + p * 16384;
    const short* lBp = lds + 49152 + p * 8192;

    // ---- cluster 0: k-slice 0; stage next A tile ----
    GQ_STAGE_A(pn, tn);
    v8s a[4], b[4];
#pragma unroll
    for (int mt = 0; mt < 4; ++mt) a[mt] = *(const v8s*)(lAp + aoff[mt] + csw0);
#pragma unroll
    for (int nt = 0; nt < 4; ++nt) b[nt] = *(const v8s*)(lBp + boff[nt] + csw0);
    __builtin_amdgcn_s_setprio(1);
#pragma unroll
    for (int mt = 0; mt < 4; ++mt)
#pragma unroll
      for (int nt = 0; nt < 4; ++nt)
        acc[mt][nt] = __builtin_amdgcn_mfma_f32_16x16x32_bf16(a[mt], b[nt], acc[mt][nt], 0, 0, 0);
    __builtin_amdgcn_s_setprio(0);

    // ---- cluster 1: k-slice 1; stage next B tile ----
    GQ_STAGE_B(pn, tn);
#pragma unroll
    for (int mt = 0; mt < 4; ++mt) a[mt] = *(const v8s*)(lAp + aoff[mt] + csw1);
#pragma unroll
    for (int nt = 0; nt < 4; ++nt) b[nt] = *(const v8s*)(lBp + boff[nt] + csw1);
    __builtin_amdgcn_s_setprio(1);
#pragma unroll
    for (int mt = 0; mt < 4; ++mt)
#pragma unroll
      for (int nt = 0; nt < 4; ++nt)
        acc[mt][nt] = __builtin_amdgcn_mfma_f32_16x16x32_bf16(a[mt], b[nt], acc[mt][nt], 0, 0, 0);
    __builtin_amdgcn_s_setprio(0);

    // counted wait: only t+2's 6 loads may remain outstanding -> t+1 resident
    asm volatile("s_waitcnt vmcnt(6) lgkmcnt(0)" ::: "memory");
    __builtin_amdgcn_s_barrier();
    p = (p == 2) ? 0 : p + 1;
    pn = (pn == 2) ? 0 : pn + 1;
  }
  asm volatile("s_waitcnt vmcnt(0)" ::: "memory");  // drain clamped tail loads

  // ---- epilogue ----
  const int selu = n0 >> 10;            // uniform per block (128 | 1024)
  if (selu < 2) {
    short* obase = (selu == 0) ? Qo : Ko;
    const float sc = (selu == 0) ? 0.18033688011112042f : 1.0f;  // fold softmax scale into Q
#pragma unroll
    for (int nt = 0; nt < 4; ++nt) {
      int n = (n0 + wn + nt * 16 + l16) & 1023;
      int h = n >> 6, d = n & 63;
#pragma unroll
      for (int mt = 0; mt < 4; ++mt) {
        int m = m0 + wm + mt * 16 + quad * 4;
        int b_ = m >> 11, tt_ = m & 2047;
        size_t base = (size_t)((b_ * 16 + h) * 2048 + tt_) * 64 + d;
#pragma unroll
        for (int r = 0; r < 4; ++r)
          obase[base + (size_t)r * 64] = f2bf(acc[mt][nt][r] * sc);
      }
    }
  } else {
    // V: write directly transposed -> Vt [bh][64][2048]
#pragma unroll
    for (int nt = 0; nt < 4; ++nt) {
      int n = (n0 + wn + nt * 16 + l16) & 1023;
      int h = n >> 6, d = n & 63;
#pragma unroll
      for (int mt = 0; mt < 4; ++mt) {
        int m = m0 + wm + mt * 16 + quad * 4;
        int b_ = m >> 11, tt_ = m & 2047;
        int2 dw;
        dw.x = (int)pk_bf16(acc[mt][nt][0], acc[mt][nt][1]);
        dw.y = (int)pk_bf16(acc[mt][nt][2], acc[mt][nt][3]);
        *(int2*)(Vt + ((size_t)(b_ * 16 + h) * 64 + d) * 2048 + tt_) = dw;
      }
    }
  }
}

// ---------------- flash attention (S^T form, pipelined LDS-staged K/V) -------------
// grid: 1024 blocks = 64 bh x 16 chunk-slots; LDS 40 KB, launch_bounds(256,2)
// (NOT (256,4): the hard VGPR cap caused scratch spills, round 7).
// Slot->chunk nibble-LUT: each CU's slot set {s,s+4,s+8,s+12} sums to 68 tiles.
// block 256 = 4 waves x 32 q-rows = 128 q-rows (one chunk per block).
// CANONICAL 2-PHASE loop (T3 minimum recipe): per tile
//   [issue STAGE(t+1) -> compute(t) -> vmcnt(0) -> barrier]
// ONE barrier per tile (was 2). Stage safety: STAGE(t+1) writes buf p^1, last read
// at compute(t-1), ordered by the end-of-(t-1) barrier. Residency: compute(t)'s buf
// proven by end-of-(t-1) vmcnt(0)+barrier. Stage has the full compute phase to land.
// Register discipline: QK^T for BOTH qs first into sT[2][4] (aK dies), then aV +
// exp/pack/PV per qs. lP: per-wave 16-row XOR-swizzled region, qs-sequential
// write->read (wave-private, in-order DS). Softmax: fixed-max exp2; Q pre-scaled.

#define ASTAGE(P, KB)                                                             \
  GLDS(K + qkbase + (size_t)((KB) + r0) * 64 + cl0 * 8, lK + (P) * 4096 + tid * 8);          \
  GLDS(K + qkbase + (size_t)((KB) + r1) * 64 + cl1 * 8, lK + (P) * 4096 + tid * 8 + 2048);   \
  GLDS(Vt + vtbase + (size_t)r0 * 2048 + (KB) + cl0 * 8, lV + (P) * 4096 + tid * 8);         \
  GLDS(Vt + vtbase + (size_t)r1 * 2048 + (KB) + cl1 * 8, lV + (P) * 4096 + tid * 8 + 2048)

__global__ __launch_bounds__(256, 2) void attn(const short* __restrict__ Q,
                                               const short* __restrict__ K,
                                               const short* __restrict__ Vt,
                                               short* __restrict__ AO) {
  __shared__ short lK[2 * 64 * 64];     // 16 KB double-buffered K tiles (swizzled)
  __shared__ short lV[2 * 64 * 64];     // 16 KB double-buffered V^T tiles (swizzled)
  __shared__ short lP[4 * 16 * 64];     // 8 KB P round-trip (per-wave 16x64 swizzled)
  const int tid = threadIdx.x;
  const int w = tid >> 6, lane = tid & 63, quad = lane >> 4, l16 = lane & 15;
  const int bh = blockIdx.x & 63;
  const int slot = blockIdx.x >> 6;     // 0..15
  const int c = (int)((0x5410672398DCABEFull >> (slot * 4)) & 15ull);
  const unsigned psel = 0x07060302u;        // v_perm: {hi16(b), hi16(a)}
  short* pw = lP + w * 1024;                // 16 rows x 64 cols (swizzled)
  const size_t qkbase = (size_t)bh * 2048 * 64;
  const size_t vtbase = (size_t)bh * 64 * 2048;
  const int b_ = bh >> 4, h = bh & 15;

  // staging map: thread handles chunks c0=tid, c1=tid+256 of each tile
  const int r0 = tid >> 3, cp = tid & 7;
  const int cl0 = cp ^ (r0 & 7);
  const int r1 = r0 + 32;
  const int cl1 = cp ^ (r1 & 7);

  // fragment LDS offsets (shorts): row*64 + (col8log ^ (l16&7))*8
  const int swz = l16 & 7;
  const int ph0 = (quad ^ swz) * 8;           // col8log = quad   (k 0..31)
  const int ph1 = ((quad + 4) ^ swz) * 8;     // col8log = quad+4 (k 32..63)

  const int qc = c * 128 + w * 32;            // this wave's first q-row

  // Q fragments (B-operand of S^T): B[k=d][n=qrow], two 16-row subsets
  v8s bQ[2][2];
#pragma unroll
  for (int qs = 0; qs < 2; ++qs) {
    const short* qb = Q + qkbase + (size_t)(qc + qs * 16 + l16) * 64 + quad * 8;
    bQ[qs][0] = *(const v8s*)(qb);
    bQ[qs][1] = *(const v8s*)(qb + 32);
  }
  v4f accO[2][4];
#pragma unroll
  for (int qs = 0; qs < 2; ++qs)
#pragma unroll
    for (int g = 0; g < 4; ++g) accO[qs][g] = (v4f){0.f, 0.f, 0.f, 0.f};
  float lrun[2] = {0.f, 0.f};

  const int nst = 2 * c + 2;                  // 64-key tiles covering the 128-row chunk

  // prologue: stage tile 0, drain, barrier (tile 0 resident for all waves)
  ASTAGE(0, 0);
  asm volatile("s_waitcnt vmcnt(0)" ::: "memory");
  __builtin_amdgcn_s_barrier();

  for (int kt = 0; kt < nst; ++kt) {
    const int p = kt & 1;
    const int kb = kt * 64;
    if (kt + 1 < nst) {                 // block-uniform; overlaps the compute below
      ASTAGE(p ^ 1, kb + 64);
    }
    const short* lKp = lK + p * 4096;
    const short* lVp = lV + p * 4096;

    const bool act0 = kb < qc + 16;     // qs=0 has unmasked keys this stage
    const bool act1 = kb < qc + 32;     // qs=1 (superset of act0)
    if (act1) {                         // wave-uniform
      // ---- phase A: K fragments + QK^T for both q-subsets (aK dies after) ----
      v4f sT[2][4];
      {
        v8s aK[4][2];
#pragma unroll
        for (int mt = 0; mt < 4; ++mt) {
          const short* kr = lKp + (mt * 16 + l16) * 64;
          aK[mt][0] = *(const v8s*)(kr + ph0);
          aK[mt][1] = *(const v8s*)(kr + ph1);
        }
        __builtin_amdgcn_s_setprio(1);
#pragma unroll
        for (int qs = 0; qs < 2; ++qs) {
          if (qs == 0 ? !act0 : false) continue;
#pragma unroll
          for (int mt = 0; mt < 4; ++mt) {
            v4f t = (v4f){0.f, 0.f, 0.f, 0.f};
            t = __builtin_amdgcn_mfma_f32_16x16x32_bf16(aK[mt][0], bQ[qs][0], t, 0, 0, 0);
            t = __builtin_amdgcn_mfma_f32_16x16x32_bf16(aK[mt][1], bQ[qs][1], t, 0, 0, 0);
            sT[qs][mt] = t;
          }
        }
        __builtin_amdgcn_s_setprio(0);
      }
      // ---- phase B: V fragments + per-qs exp/pack/PV (shared 16-row lP) ----
      v8s aV[4][2];
#pragma unroll
      for (int g = 0; g < 4; ++g) {
        const short* vr = lVp + (g * 16 + l16) * 64;
        aV[g][0] = *(const v8s*)(vr + ph0);
        aV[g][1] = *(const v8s*)(vr + ph1);
      }
#pragma unroll
      for (int qs = 0; qs < 2; ++qs) {
        if (qs == 0 ? !act0 : false) continue;
        const int rbase = qc + qs * 16;
        if (kb + 63 >= rbase) {         // diagonal-overlap: element mask
          const int kq = kb + quad * 4 - (rbase + l16);
#pragma unroll
          for (int mt = 0; mt < 4; ++mt)
#pragma unroll
            for (int r = 0; r < 4; ++r)
              if (kq + mt * 16 + r > 0) sT[qs][mt][r] = -__builtin_inff();
        }
        float ls = lrun[qs];
#pragma unroll
        for (int mt = 0; mt < 4; ++mt) {
          float p0 = EXP2(sT[qs][mt][0]);   // Q pre-scaled: exp2 directly
          float p1 = EXP2(sT[qs][mt][1]);
          float p2 = EXP2(sT[qs][mt][2]);
          float p3 = EXP2(sT[qs][mt][3]);
          ls += (p0 + p1) + (p2 + p3);
          int2 dw;
          dw.x = (int)__builtin_amdgcn_perm(__float_as_uint(p1), __float_as_uint(p0), psel);
          dw.y = (int)__builtin_amdgcn_perm(__float_as_uint(p3), __float_as_uint(p2), psel);
          // swizzled write: row l16, cols mt*16+quad*4 .. +3 (XOR on 16B block idx)
          *(int2*)&pw[l16 * 64 + ((mt * 16 + quad * 4) ^ (swz * 8))] = dw;
        }
        lrun[qs] = ls;
        // ---- PV: read this qs's P (same swizzle pattern as K/V reads) ----
        v8s bP0 = *(const v8s*)&pw[l16 * 64 + ph0];
        v8s bP1 = *(const v8s*)&pw[l16 * 64 + ph1];
        __builtin_amdgcn_s_setprio(1);
#pragma unroll
        for (int g = 0; g < 4; ++g) {
          accO[qs][g] = __builtin_amdgcn_mfma_f32_16x16x32_bf16(aV[g][0], bP0, accO[qs][g], 0, 0, 0);
          accO[qs][g] = __builtin_amdgcn_mfma_f32_16x16x32_bf16(aV[g][1], bP1, accO[qs][g], 0, 0, 0);
        }
        __builtin_amdgcn_s_setprio(0);
      }
    }
    // single sync point per tile: drain this iter's stage loads, then barrier.
    asm volatile("s_waitcnt vmcnt(0)" ::: "memory");
    __builtin_amdgcn_s_barrier();
  }

  // ---- epilogue: finish row-sums (across the 4 quads), normalize, store O^T ----
#pragma unroll
  for (int qs = 0; qs < 2; ++qs) {
    float ls = lrun[qs];
    ls += __shfl_xor(ls, 16);
    ls += __shfl_xor(ls, 32);
    float inv = __builtin_amdgcn_rcpf(ls);
    int t = qc + qs * 16 + l16;
    short* ao = AO + ((size_t)(b_ * 2048 + t)) * 1024 + h * 64 + quad * 4;
#pragma unroll
    for (int g = 0; g < 4; ++g) {
      int2 dw;
      dw.x = (int)pk_bf16(accO[qs][g][0] * inv, accO[qs][g][1] * inv);
      dw.y = (int)pk_bf16(accO[qs][g][2] * inv, accO[qs][g][3] * inv);
      *(int2*)(ao + g * 16) = dw;       // d = g*16 + quad*4 + {0..3}
    }
  }
}

#undef ASTAGE

// ---------------- output projection: out = AO @ Wo^T + bo (fp32 out) ----------------
// Same BK=64 triple-buffer structure as gemm_qkv (measured +9% on same-shape
// sibling): BM=256 BN=128 BK=64, 144 KB LDS, 512 thr, grid 32x8 = 256 = 1 wave.

#define GO_STAGE_A(P, T) do {                                                     \
  _Pragma("unroll") for (int i_ = 0; i_ < 4; ++i_)                                \
    GLDS(AO + (size_t)(m0 + rA + i_ * 64) * 1024 + (T) * 64 + cbl * 8,            \
         lds + (P) * 16384 + (tid + i_ * 512) * 8); } while (0)

#define GO_STAGE_B(P, T) do {                                                     \
  _Pragma("unroll") for (int i_ = 0; i_ < 2; ++i_)                                \
    GLDS(Wot + (size_t)(n0 + rA + i_ * 64) * 1024 + (T) * 64 + cbl * 8,           \
         lds + 49152 + (P) * 8192 + (tid + i_ * 512) * 8); } while (0)

__global__ __launch_bounds__(512) void gemm_out(const short* __restrict__ AO,
                                                const short* __restrict__ Wot,
                                                const float* __restrict__ bo,
                                                float* __restrict__ out) {
  __shared__ short lds[73728];          // 144 KB: A bufs 3x[256][64] | B bufs 3x[128][64]
  const int tid = threadIdx.x;
  const int lane = tid & 63, quad = lane >> 4, l16 = lane & 15;
  const int wave = tid >> 6;
  const int m0 = blockIdx.x * 256, n0 = blockIdx.y * 128;
  const int wm = (wave >> 1) * 64, wn = (wave & 1) * 64;

  const int rA = tid >> 3;
  const int cbl = (tid & 7) ^ (rA & 7);

  const int swz = l16 & 7;
  const int csw0 = (quad ^ swz) * 8;
  const int csw1 = ((4 + quad) ^ swz) * 8;
  int aoff[4], boff[4];
#pragma unroll
  for (int mt = 0; mt < 4; ++mt) aoff[mt] = (wm + mt * 16 + l16) * 64;
#pragma unroll
  for (int nt = 0; nt < 4; ++nt) boff[nt] = (wn + nt * 16 + l16) * 64;

  v4f acc[4][4];
#pragma unroll
  for (int i = 0; i < 4; ++i)
#pragma unroll
    for (int j = 0; j < 4; ++j) acc[i][j] = (v4f){0.f, 0.f, 0.f, 0.f};

  GO_STAGE_A(0, 0); GO_STAGE_B(0, 0);
  GO_STAGE_A(1, 1); GO_STAGE_B(1, 1);
  asm volatile("s_waitcnt vmcnt(6)" ::: "memory");
  __builtin_amdgcn_s_barrier();

  int p = 0, pn = 2;
#pragma unroll 1
  for (int t = 0; t < 16; ++t) {
    int tn = t + 2; if (tn > 15) tn = 15;
    const short* lAp = lds + p * 16384;
    const short* lBp = lds + 49152 + p * 8192;

    GO_STAGE_A(pn, tn);
    v8s a[4], b[4];
#pragma unroll
    for (int mt = 0; mt < 4; ++mt) a[mt] = *(const v8s*)(lAp + aoff[mt] + csw0);
#pragma unroll
    for (int nt = 0; nt < 4; ++nt) b[nt] = *(const v8s*)(lBp + boff[nt] + csw0);
    __builtin_amdgcn_s_setprio(1);
#pragma unroll
    for (int mt = 0; mt < 4; ++mt)
#pragma unroll
      for (int nt = 0; nt < 4; ++nt)
        acc[mt][nt] = __builtin_amdgcn_mfma_f32_16x16x32_bf16(a[mt], b[nt], acc[mt][nt], 0, 0, 0);
    __builtin_amdgcn_s_setprio(0);

    GO_STAGE_B(pn, tn);
#pragma unroll
    for (int mt = 0; mt < 4; ++mt) a[mt] = *(const v8s*)(lAp + aoff[mt] + csw1);
#pragma unroll
    for (int nt = 0; nt < 4; ++nt) b[nt] = *(const v8s*)(lBp + boff[nt] + csw1);
    __builtin_amdgcn_s_setprio(1);
#pragma unroll
    for (int mt = 0; mt < 4; ++mt)
#pragma unroll
      for (int nt = 0; nt < 4; ++nt)
        acc[mt][nt] = __builtin_amdgcn_mfma_f32_16x16x32_bf16(a[mt], b[nt], acc[mt][nt], 0, 0, 0);
    __builtin_amdgcn_s_setprio(0);

    asm volatile("s_waitcnt vmcnt(6) lgkmcnt(0)" ::: "memory");
    __builtin_amdgcn_s_barrier();
    p = (p == 2) ? 0 : p + 1;
    pn = (pn == 2) ? 0 : pn + 1;
  }
  asm volatile("s_waitcnt vmcnt(0)" ::: "memory");

  // epilogue: fp32 + bias
#pragma unroll
  for (int nt = 0; nt < 4; ++nt) {
    int n = n0 + wn + nt * 16 + l16;
    float bias = bo[n];
#pragma unroll
    for (int mt = 0; mt < 4; ++mt) {
      int m = m0 + wm + mt * 16 + quad * 4;
#pragma unroll
      for (int r = 0; r < 4; ++r)
        out[(size_t)(m + r) * 1024 + n] = acc[mt][nt][r] + bias;
    }
  }
}

// ---------------- launch ----------------

extern "C" void kernel_launch(void* const* d_in, const int* in_sizes, int n_in,
                              void* d_out, int out_size, void* d_ws, size_t ws_size,
                              hipStream_t stream) {
  const float* x  = (const float*)d_in[0];
  const float* Wq = (const float*)d_in[1];
  const float* Wk = (const float*)d_in[2];
  const float* Wv = (const float*)d_in[3];
  const float* Wo = (const float*)d_in[4];
  const float* bo = (const float*)d_in[5];
  float* out = (float*)d_out;
  char* ws = (char*)d_ws;

  short* Xb  = (short*)(ws);                          // 16 MB (reused as AO after QKV GEMM)
  short* Wt  = (short*)(ws + (16u << 20));            // 6 MB
  short* Wot = (short*)(ws + (22u << 20));            // 2 MB
  short* Q   = (short*)(ws + (24u << 20));            // 16 MB
  short* K   = (short*)(ws + (40u << 20));            // 16 MB
  short* Vt  = (short*)(ws + (56u << 20));            // 16 MB  -> total 72 MB

  prep<<<9984, 256, 0, stream>>>(x, Wq, Wk, Wv, Wo, Xb, Wot, Wt);
  gemm_qkv<<<dim3(32, 24), 512, 0, stream>>>(Xb, Wt, Q, K, Vt);
  attn<<<1024, 256, 0, stream>>>(Q, K, Vt, Xb);  // AO aliases Xb, 16 slots/bh
  gemm_out<<<dim3(32, 8), 512, 0, stream>>>(Xb, Wot, bo, out);
}